// Round 1
// baseline (384.290 us; speedup 1.0000x reference)
//
#include <hip/hip_runtime.h>
#include <math.h>

#define IN_DIM   128
#define OUT_DIM  128
#define EDGE_DIM 32
#define NUM_HEADS 8
#define HEAD_DIM 16
#define SCALE 0.25f

typedef __attribute__((ext_vector_type(8))) short bf16x8;
typedef __attribute__((ext_vector_type(4))) float f32x4;
typedef __attribute__((ext_vector_type(4))) unsigned int u32x4;

__device__ inline unsigned short f2bf(float x) {   // round-to-nearest-even
    unsigned int u = __float_as_uint(x);
    unsigned int r = u + 0x7fff + ((u >> 16) & 1);
    return (unsigned short)(r >> 16);
}
__device__ inline float bflo(unsigned int u) { return __uint_as_float(u << 16); }
__device__ inline float bfhi(unsigned int u) { return __uint_as_float(u & 0xffff0000u); }

// ---------------------------------------------------------------------------
// setup: [zero counts] + [W^T bf16] + [We head-sum reduce] + [X -> bf16]
// grid = nbz + nbw + 1 + nbx
// ---------------------------------------------------------------------------
__global__ __launch_bounds__(256) void setup_kernel(
    int* __restrict__ counts, int n_nodes, int nbz,
    const float* __restrict__ Wq, const float* __restrict__ Wk,
    const float* __restrict__ Wv, unsigned short* __restrict__ WtB, int nbw,
    const float* __restrict__ We, const float* __restrict__ be,
    float* __restrict__ WeR, float* __restrict__ beR,
    const float* __restrict__ X, unsigned short* __restrict__ Xb)
{
    const int bx = blockIdx.x;
    const int t  = threadIdx.x;
    if (bx < nbz) {                                   // zero counts
        const int i = bx * 256 + t;
        if (i < n_nodes) counts[i] = 0;
    } else if (bx < nbz + nbw) {                      // W[k][n] -> WtB[mat][n][k]
        const int idx = (bx - nbz) * 256 + t;
        const int mat = idx >> 14;
        const int rem = idx & 16383;
        const int n = rem >> 7, k = rem & 127;
        const float* W = (mat == 0) ? Wq : (mat == 1) ? Wk : Wv;
        WtB[mat * 16384 + n * 128 + k] = f2bf(W[k * 128 + n]);
    } else if (bx == nbz + nbw) {                     // We reduce
        const int k = t >> 3, h = t & 7;
        float s = 0.f;
#pragma unroll
        for (int d = 0; d < HEAD_DIM; ++d) s += We[k * OUT_DIM + h * HEAD_DIM + d];
        WeR[k * NUM_HEADS + h] = s;
        if (t < NUM_HEADS) {
            float sb = 0.f;
#pragma unroll
            for (int d = 0; d < HEAD_DIM; ++d) sb += be[t * HEAD_DIM + d];
            beR[t] = sb;
        }
    } else {                                          // X f32 -> bf16 (8/thread)
        const int i = (bx - (nbz + nbw + 1)) * 256 + t;
        if (i < n_nodes * 16) {
            const f32x4* xr = (const f32x4*)(X + (size_t)i * 8);
            const f32x4 x0 = xr[0], x1 = xr[1];
            u32x4 p;
            p[0] = (unsigned)f2bf(x0[0]) | ((unsigned)f2bf(x0[1]) << 16);
            p[1] = (unsigned)f2bf(x0[2]) | ((unsigned)f2bf(x0[3]) << 16);
            p[2] = (unsigned)f2bf(x1[0]) | ((unsigned)f2bf(x1[1]) << 16);
            p[3] = (unsigned)f2bf(x1[2]) | ((unsigned)f2bf(x1[3]) << 16);
            *(u32x4*)(Xb + (size_t)i * 8) = p;
        }
    }
}

// ---------------------------------------------------------------------------
// megakernel: blocks [0,nbq)       = merged Q+K+V bf16 MFMA (A-frags reused);
//             blocks [nbq,nbq+nbh) = edge histogram (rank) only.
// ---------------------------------------------------------------------------
__global__ __launch_bounds__(256) void mega_kernel(
    const unsigned short* __restrict__ Xb, const unsigned short* __restrict__ WtB,
    const float* __restrict__ bq, const float* __restrict__ bk,
    const float* __restrict__ bv,
    unsigned short* __restrict__ QVb, unsigned short* __restrict__ Kb,
    int n_nodes, int nbq,
    const int* __restrict__ el, int* __restrict__ counts,
    int* __restrict__ rank, int n_edges)
{
    const int bx = blockIdx.x;
    const int t  = threadIdx.x;

    if (bx >= nbq) {
        // ---------------- edge histogram only ----------------
        const int e = (bx - nbq) * 256 + t;
        if (e < n_edges) {
            const int2 ed = ((const int2*)el)[e];
            rank[e] = atomicAdd(&counts[ed.y], 1);
        }
        return;
    }

    // ---------------- merged QKV via bf16 MFMA ----------------
    __shared__ unsigned short stg[4][16][136];

    const int wave = t >> 6, lane = t & 63;
    const int quad = lane >> 4, li = lane & 15;
    const int m0 = bx * 64 + wave * 16;
    int mrow = m0 + li;
    if (mrow >= n_nodes) mrow = n_nodes - 1;

    // A-fragments: loaded once (bf16 direct), reused for Q, K and V
    bf16x8 a[4];
#pragma unroll
    for (int ks = 0; ks < 4; ++ks)
        a[ks] = *(const bf16x8*)(Xb + (size_t)mrow * 128 + ks * 32 + quad * 8);

    const int R = lane >> 2;
    const int cc = lane & 3;
    const int node = m0 + R;

#pragma unroll
    for (int which = 0; which < 3; ++which) {
        const float* bias = (which == 0) ? bq : (which == 1) ? bk : bv;
        const unsigned short* Wg = WtB + which * 16384;

        f32x4 acc[8];
#pragma unroll
        for (int nt = 0; nt < 8; ++nt) acc[nt] = (f32x4){0.f, 0.f, 0.f, 0.f};

#pragma unroll
        for (int ks = 0; ks < 4; ++ks) {
#pragma unroll
            for (int nt = 0; nt < 8; ++nt) {
                const bf16x8 b = *(const bf16x8*)(Wg + (nt * 16 + li) * 128 + ks * 32 + quad * 8);
                acc[nt] = __builtin_amdgcn_mfma_f32_16x16x32_bf16(a[ks], b, acc[nt], 0, 0, 0);
            }
        }

#pragma unroll
        for (int nt = 0; nt < 8; ++nt) {
            const float bb = bias[nt * 16 + li];
#pragma unroll
            for (int r = 0; r < 4; ++r)
                stg[wave][quad * 4 + r][nt * 16 + li] = f2bf(acc[nt][r] + bb);
        }
        __syncthreads();

        if (node < n_nodes) {
            const u32x4* s = (const u32x4*)(&stg[wave][R][cc * 32]);
            u32x4 d0 = s[0], d1 = s[1], d2 = s[2], d3 = s[3];
            unsigned short* dp =
                (which == 0) ? (QVb + (size_t)node * 256 + cc * 32)
              : (which == 1) ? (Kb  + (size_t)node * 128 + cc * 32)
              :                (QVb + (size_t)node * 256 + 128 + cc * 32);
            u32x4* d = (u32x4*)dp;
            d[0] = d0; d[1] = d1; d[2] = d2; d[3] = d3;
        }
        __syncthreads();
    }
}

// ---------------------------------------------------------------------------
// scan: phase 1 block sums; phase 2 fused into phase 3.
// ---------------------------------------------------------------------------
__global__ __launch_bounds__(256) void scan1_kernel(
    const int* __restrict__ counts, int* __restrict__ bsums, int n)
{
    __shared__ int lds[256];
    const int i = blockIdx.x * 256 + threadIdx.x;
    lds[threadIdx.x] = (i < n) ? counts[i] : 0;
    __syncthreads();
    for (int off = 128; off > 0; off >>= 1) {
        if (threadIdx.x < off) lds[threadIdx.x] += lds[threadIdx.x + off];
        __syncthreads();
    }
    if (threadIdx.x == 0) bsums[blockIdx.x] = lds[0];
}

__global__ __launch_bounds__(256) void scan3_kernel(
    const int* __restrict__ counts, const int* __restrict__ bsums,
    int* __restrict__ offsets, int n, int n_edges, int nb)
{
    __shared__ int lds[256];
    const int t = threadIdx.x;

    int v = (t < nb) ? bsums[t] : 0;
    lds[t] = v;
    __syncthreads();
    for (int off = 1; off < 256; off <<= 1) {
        const int u = (t >= off) ? lds[t - off] : 0;
        __syncthreads();
        lds[t] += u;
        __syncthreads();
    }
    const int base = (blockIdx.x > 0) ? lds[blockIdx.x - 1] : 0;
    __syncthreads();

    const int i = blockIdx.x * 256 + t;
    const int c = (i < n) ? counts[i] : 0;
    lds[t] = c;
    __syncthreads();
    for (int off = 1; off < 256; off <<= 1) {
        const int u = (t >= off) ? lds[t - off] : 0;
        __syncthreads();
        lds[t] += u;
        __syncthreads();
    }
    if (i < n) offsets[i] = base + lds[t] - c;
    if (blockIdx.x == 0 && t == 0) offsets[n] = n_edges;
}

// ---------------------------------------------------------------------------
// scatter: NO atomics. pos = offsets[dst] + rank[e].
// Fused edge-bias GEMV (weights via thread-uniform scalar loads -> SGPRs).
// record = 32B: [src:4 | pad:4 | ebias bf16 x8:16 | pad:8]
// ---------------------------------------------------------------------------
__global__ __launch_bounds__(256) void scatter_kernel(
    const int* __restrict__ el, const int* __restrict__ rank,
    const float* __restrict__ ef,
    const float* __restrict__ WeR, const float* __restrict__ beR,
    const int* __restrict__ offsets, unsigned int* __restrict__ recs,
    int n_edges)
{
    const int e = blockIdx.x * 256 + threadIdx.x;
    if (e >= n_edges) return;
    const int2 ed = ((const int2*)el)[e];
    const int pos = offsets[ed.y] + rank[e];

    float acc[NUM_HEADS];
#pragma unroll
    for (int h = 0; h < NUM_HEADS; ++h) acc[h] = beR[h];   // uniform -> s_load

    const f32x4* efr = (const f32x4*)(ef + (size_t)e * EDGE_DIM);
#pragma unroll
    for (int kk = 0; kk < 8; ++kk) {
        const f32x4 f = efr[kk];
#pragma unroll
        for (int c = 0; c < 4; ++c) {
            const float* wr = WeR + (kk * 4 + c) * NUM_HEADS;  // uniform, contiguous 32B
#pragma unroll
            for (int h = 0; h < NUM_HEADS; ++h)
                acc[h] = fmaf(f[c], wr[h], acc[h]);
        }
    }

    u32x4 r0, r1;
    r0[0] = (unsigned)ed.x;
    r0[1] = 0;
    r0[2] = (unsigned)f2bf(acc[0]) | ((unsigned)f2bf(acc[1]) << 16);
    r0[3] = (unsigned)f2bf(acc[2]) | ((unsigned)f2bf(acc[3]) << 16);
    r1[0] = (unsigned)f2bf(acc[4]) | ((unsigned)f2bf(acc[5]) << 16);
    r1[1] = (unsigned)f2bf(acc[6]) | ((unsigned)f2bf(acc[7]) << 16);
    r1[2] = 0; r1[3] = 0;
    u32x4* rp = (u32x4*)(recs + (size_t)pos * 8);
    rp[0] = r0;
    rp[1] = r1;
}

// ---------------------------------------------------------------------------
// aggregate: 2 edges per wave (32 lanes/edge, 4 elems/lane). Unchanged.
// ---------------------------------------------------------------------------
__global__ __launch_bounds__(256) void aggregate_kernel(
    const unsigned short* __restrict__ QVb, const unsigned short* __restrict__ Kb,
    const int* __restrict__ offsets, const unsigned int* __restrict__ recs,
    float* __restrict__ out, int n_nodes)
{
    const int gw   = (blockIdx.x * 256 + threadIdx.x) >> 6;
    const int lane = threadIdx.x & 63;
    const int half = lane >> 5, ln = lane & 31;
    const int node = gw * 2 + half;
    const int h = ln >> 2;
    const bool valid = node < n_nodes;

    int beg = 0, end = 0;
    if (valid) { beg = offsets[node]; end = offsets[node + 1]; }
    const int cnt = end - beg;
    const int mcnt = max(cnt, __shfl_xor(cnt, 32));

    float k0 = 0.f, k1 = 0.f, k2 = 0.f, k3 = 0.f;
    if (valid) {
        const uint2 kp = ((const uint2*)(Kb + (size_t)node * 128))[ln];
        k0 = bflo(kp.x); k1 = bfhi(kp.x); k2 = bflo(kp.y); k3 = bfhi(kp.y);
    }

    float a0 = 0.f, a1 = 0.f, a2 = 0.f, a3 = 0.f;

    uint2 qp = make_uint2(0, 0), vp = make_uint2(0, 0);
    float eb = 0.f;
    if (cnt > 0) {
        const unsigned int* rb = recs + (size_t)beg * 8;
        const int src = (int)rb[0];
        const unsigned int ebp = rb[2 + (h >> 1)];
        eb = (h & 1) ? bfhi(ebp) : bflo(ebp);
        const uint2* r = (const uint2*)(QVb + (size_t)src * 256);
        qp = r[ln];
        vp = r[32 + ln];
    }

    for (int i = 0; i < mcnt; ++i) {
        uint2 nqp = qp, nvp = vp;
        float neb = eb;
        if (i + 1 < cnt) {   // prefetch next edge
            const unsigned int* rb = recs + (size_t)(beg + i + 1) * 8;
            const int ns = (int)rb[0];
            const unsigned int ebp = rb[2 + (h >> 1)];
            neb = (h & 1) ? bfhi(ebp) : bflo(ebp);
            const uint2* r = (const uint2*)(QVb + (size_t)ns * 256);
            nqp = r[ln];
            nvp = r[32 + ln];
        }

        const float q0 = bflo(qp.x), q1 = bfhi(qp.x);
        const float q2 = bflo(qp.y), q3 = bfhi(qp.y);
        float p = fmaf(q0, k0, fmaf(q1, k1, fmaf(q2, k2, q3 * k3)));
        p += __shfl_xor(p, 1);
        p += __shfl_xor(p, 2);
        const float score = fmaf(p, SCALE, eb);

        float mx = score;
        mx = fmaxf(mx, __shfl_xor(mx, 4));
        mx = fmaxf(mx, __shfl_xor(mx, 8));
        mx = fmaxf(mx, __shfl_xor(mx, 16));
        const float ex = __expf(score - mx);
        float den = ex;
        den += __shfl_xor(den, 4);
        den += __shfl_xor(den, 8);
        den += __shfl_xor(den, 16);
        const float w = __fdividef(ex, den);

        if (i < cnt) {
            a0 = fmaf(w, bflo(vp.x), a0);
            a1 = fmaf(w, bfhi(vp.x), a1);
            a2 = fmaf(w, bflo(vp.y), a2);
            a3 = fmaf(w, bfhi(vp.y), a3);
        }
        qp = nqp; vp = nvp; eb = neb;
    }

    if (valid) {
        f32x4 o; o[0] = a0; o[1] = a1; o[2] = a2; o[3] = a3;
        *(((f32x4*)(out + (size_t)node * OUT_DIM)) + ln) = o;
    }
}

// ---------------------------------------------------------------------------
extern "C" void kernel_launch(void* const* d_in, const int* in_sizes, int n_in,
                              void* d_out, int out_size, void* d_ws, size_t ws_size,
                              hipStream_t stream)
{
    const float* X   = (const float*)d_in[0];
    const float* ef  = (const float*)d_in[1];
    const float* Wq  = (const float*)d_in[2];
    const float* bq  = (const float*)d_in[3];
    const float* Wk  = (const float*)d_in[4];
    const float* bk  = (const float*)d_in[5];
    const float* Wv  = (const float*)d_in[6];
    const float* bv  = (const float*)d_in[7];
    const float* We  = (const float*)d_in[8];
    const float* be  = (const float*)d_in[9];
    const int*   el  = (const int*)d_in[10];

    const int n_nodes = in_sizes[0] / IN_DIM;
    const int n_edges = in_sizes[10] / 2;

    char* w = (char*)d_ws;
    auto alloc = [&](size_t bytes) { char* p = w; w += (bytes + 255) & ~(size_t)255; return p; };

    unsigned short* QVb    = (unsigned short*)alloc((size_t)n_nodes * 256 * 2);
    unsigned short* Kb     = (unsigned short*)alloc((size_t)n_nodes * 128 * 2);
    unsigned short* WtB    = (unsigned short*)alloc((size_t)3 * 128 * 128 * 2);
    unsigned short* Xb     = (unsigned short*)alloc((size_t)n_nodes * 128 * 2);
    unsigned int*   recs   = (unsigned int*)alloc((size_t)n_edges * 32);
    int* rank    = (int*)alloc((size_t)n_edges * 4);
    float* WeR   = (float*)alloc(EDGE_DIM * NUM_HEADS * 4);
    float* beR   = (float*)alloc(NUM_HEADS * 4);
    int* counts  = (int*)alloc((size_t)n_nodes * 4);
    int* offsets = (int*)alloc((size_t)(n_nodes + 1) * 4);
    int* bsums   = (int*)alloc(256 * 4);

    const int nbz = (n_nodes + 255) / 256;          // 196
    const int nbw = (3 * 128 * 128) / 256;          // 192
    const int nbx = (n_nodes * 16 + 255) / 256;     // 3125
    setup_kernel<<<nbz + nbw + 1 + nbx, 256, 0, stream>>>(
        counts, n_nodes, nbz, Wq, Wk, Wv, WtB, nbw, We, be, WeR, beR, X, Xb);

    const int nbh = (n_edges + 255) / 256;          // 3125
    const int nbq = (n_nodes + 63) / 64;            // 782
    mega_kernel<<<nbq + nbh, 256, 0, stream>>>(
        Xb, WtB, bq, bk, bv, QVb, Kb, n_nodes, nbq,
        el, counts, rank, n_edges);

    const int nb = (n_nodes + 255) / 256;           // 196
    scan1_kernel<<<nb, 256, 0, stream>>>(counts, bsums, n_nodes);
    scan3_kernel<<<nb, 256, 0, stream>>>(counts, bsums, offsets, n_nodes, n_edges, nb);

    scatter_kernel<<<nbh, 256, 0, stream>>>(
        el, rank, ef, WeR, beR, offsets, recs, n_edges);

    const int nwaves = (n_nodes + 1) / 2;
    aggregate_kernel<<<(nwaves * 64 + 255) / 256, 256, 0, stream>>>(
        QVb, Kb, offsets, recs, (float*)d_out, n_nodes);
}

// Round 2
// 335.382 us; speedup vs baseline: 1.1458x; 1.1458x over previous
//
#include <hip/hip_runtime.h>
#include <math.h>

#define IN_DIM   128
#define OUT_DIM  128
#define EDGE_DIM 32
#define NUM_HEADS 8
#define HEAD_DIM 16
#define SCALE 0.25f

typedef __attribute__((ext_vector_type(8))) short bf16x8;
typedef __attribute__((ext_vector_type(4))) float f32x4;
typedef __attribute__((ext_vector_type(4))) unsigned int u32x4;

__device__ inline unsigned short f2bf(float x) {   // round-to-nearest-even
    unsigned int u = __float_as_uint(x);
    unsigned int r = u + 0x7fff + ((u >> 16) & 1);
    return (unsigned short)(r >> 16);
}
__device__ inline float bflo(unsigned int u) { return __uint_as_float(u << 16); }
__device__ inline float bfhi(unsigned int u) { return __uint_as_float(u & 0xffff0000u); }

// ---------------------------------------------------------------------------
// setup: [zero counts] + [W^T bf16] + [We head-sum reduce] + [X -> bf16]
// grid = nbz + nbw + 1 + nbx
// ---------------------------------------------------------------------------
__global__ __launch_bounds__(256) void setup_kernel(
    int* __restrict__ counts, int n_nodes, int nbz,
    const float* __restrict__ Wq, const float* __restrict__ Wk,
    const float* __restrict__ Wv, unsigned short* __restrict__ WtB, int nbw,
    const float* __restrict__ We, const float* __restrict__ be,
    float* __restrict__ WeR, float* __restrict__ beR,
    const float* __restrict__ X, unsigned short* __restrict__ Xb)
{
    const int bx = blockIdx.x;
    const int t  = threadIdx.x;
    if (bx < nbz) {                                   // zero counts
        const int i = bx * 256 + t;
        if (i < n_nodes) counts[i] = 0;
    } else if (bx < nbz + nbw) {                      // W[k][n] -> WtB[mat][n][k]
        const int idx = (bx - nbz) * 256 + t;
        const int mat = idx >> 14;
        const int rem = idx & 16383;
        const int n = rem >> 7, k = rem & 127;
        const float* W = (mat == 0) ? Wq : (mat == 1) ? Wk : Wv;
        WtB[mat * 16384 + n * 128 + k] = f2bf(W[k * 128 + n]);
    } else if (bx == nbz + nbw) {                     // We reduce
        const int k = t >> 3, h = t & 7;
        float s = 0.f;
#pragma unroll
        for (int d = 0; d < HEAD_DIM; ++d) s += We[k * OUT_DIM + h * HEAD_DIM + d];
        WeR[k * NUM_HEADS + h] = s;
        if (t < NUM_HEADS) {
            float sb = 0.f;
#pragma unroll
            for (int d = 0; d < HEAD_DIM; ++d) sb += be[t * HEAD_DIM + d];
            beR[t] = sb;
        }
    } else {                                          // X f32 -> bf16 (8/thread)
        const int i = (bx - (nbz + nbw + 1)) * 256 + t;
        if (i < n_nodes * 16) {
            const f32x4* xr = (const f32x4*)(X + (size_t)i * 8);
            const f32x4 x0 = xr[0], x1 = xr[1];
            u32x4 p;
            p[0] = (unsigned)f2bf(x0[0]) | ((unsigned)f2bf(x0[1]) << 16);
            p[1] = (unsigned)f2bf(x0[2]) | ((unsigned)f2bf(x0[3]) << 16);
            p[2] = (unsigned)f2bf(x1[0]) | ((unsigned)f2bf(x1[1]) << 16);
            p[3] = (unsigned)f2bf(x1[2]) | ((unsigned)f2bf(x1[3]) << 16);
            *(u32x4*)(Xb + (size_t)i * 8) = p;
        }
    }
}

// ---------------------------------------------------------------------------
// megakernel:
//  blocks [0, 3*nbm)            : QKV GEMM. One `which` per block, W^T in LDS
//                                 (XOR-swizzled vs 16-way bank conflict),
//                                 M_BLOCK=256 rows (64 rows/wave, 128 MFMA/wave).
//  blocks [3*nbm, 3*nbm + nbh)  : edge blocks — hist atomic (rank) + ef GEMV
//                                 (uniform scalar-load weights) + ebias write.
//                                 Their 102 MB ef stream overlaps GEMM latency.
// ---------------------------------------------------------------------------
__global__ __launch_bounds__(256) void mega_kernel(
    const unsigned short* __restrict__ Xb, const unsigned short* __restrict__ WtB,
    const float* __restrict__ bq, const float* __restrict__ bk,
    const float* __restrict__ bv,
    unsigned short* __restrict__ QVb, unsigned short* __restrict__ Kb,
    int n_nodes, int nbm,
    const int* __restrict__ el, int* __restrict__ counts, int* __restrict__ rank,
    const float* __restrict__ ef, const float* __restrict__ WeR,
    const float* __restrict__ beR, unsigned int* __restrict__ ebias_e,
    int n_edges)
{
    __shared__ unsigned short shW[16384];   // 32KB: W^T (swizzled), reused as stg
    const int bx = blockIdx.x;
    const int t  = threadIdx.x;
    const int ngemm = 3 * nbm;

    if (bx >= ngemm) {
        // ---------------- edge blocks ----------------
        const int e = (bx - ngemm) * 256 + t;
        if (e >= n_edges) return;
        const int2 ed = ((const int2*)el)[e];
        rank[e] = atomicAdd(&counts[ed.y], 1);

        float acc[NUM_HEADS];
#pragma unroll
        for (int h = 0; h < NUM_HEADS; ++h) acc[h] = beR[h];   // uniform -> s_load

        const f32x4* efr = (const f32x4*)(ef + (size_t)e * EDGE_DIM);
#pragma unroll
        for (int kk = 0; kk < 8; ++kk) {
            const f32x4 f = efr[kk];
#pragma unroll
            for (int c = 0; c < 4; ++c) {
                const float* wr = WeR + (kk * 4 + c) * NUM_HEADS;  // uniform
#pragma unroll
                for (int h = 0; h < NUM_HEADS; ++h)
                    acc[h] = fmaf(f[c], wr[h], acc[h]);
            }
        }
        u32x4 pk;
        pk[0] = (unsigned)f2bf(acc[0]) | ((unsigned)f2bf(acc[1]) << 16);
        pk[1] = (unsigned)f2bf(acc[2]) | ((unsigned)f2bf(acc[3]) << 16);
        pk[2] = (unsigned)f2bf(acc[4]) | ((unsigned)f2bf(acc[5]) << 16);
        pk[3] = (unsigned)f2bf(acc[6]) | ((unsigned)f2bf(acc[7]) << 16);
        *(u32x4*)(ebias_e + (size_t)e * 4) = pk;
        return;
    }

    // ---------------- QKV GEMM ----------------
    const int which = bx / nbm;
    const int mb    = bx - which * nbm;
    const unsigned short* Wg = WtB + which * 16384;

    // stage W^T -> LDS, 16B chunks, XOR-swizzle row-stride-256B bank conflict away
#pragma unroll
    for (int kk = 0; kk < 8; ++kk) {
        const int c = kk * 256 + t;                 // 2048 chunks of 16B
        const u32x4 v = ((const u32x4*)Wg)[c];
        const int row = c >> 4;                     // 16 chunks per 256B row
        const int bir = (c & 15) << 4;
        *(u32x4*)((char*)shW + row * 256 + (bir ^ ((row & 7) << 4))) = v;
    }
    __syncthreads();

    const int wave = t >> 6, lane = t & 63;
    const int quad = lane >> 4, li = lane & 15;
    const int mbase = mb * 256 + wave * 64;

    int mrow[4];
#pragma unroll
    for (int m = 0; m < 4; ++m) {
        const int r_ = mbase + m * 16 + li;
        mrow[m] = (r_ < n_nodes) ? r_ : (n_nodes - 1);
    }

    f32x4 acc[4][8];
#pragma unroll
    for (int m = 0; m < 4; ++m)
#pragma unroll
        for (int nt = 0; nt < 8; ++nt) acc[m][nt] = (f32x4){0.f, 0.f, 0.f, 0.f};

#pragma unroll
    for (int ks = 0; ks < 4; ++ks) {
        bf16x8 a[4];
#pragma unroll
        for (int m = 0; m < 4; ++m)
            a[m] = *(const bf16x8*)(Xb + (size_t)mrow[m] * 128 + ks * 32 + quad * 8);
#pragma unroll
        for (int nt = 0; nt < 8; ++nt) {
            const int row = nt * 16 + li;
            const bf16x8 b = *(const bf16x8*)((const char*)shW + row * 256 +
                                ((ks * 64 + quad * 16) ^ ((row & 7) << 4)));
#pragma unroll
            for (int m = 0; m < 4; ++m)
                acc[m][nt] = __builtin_amdgcn_mfma_f32_16x16x32_bf16(a[m], b, acc[m][nt], 0, 0, 0);
        }
    }

    const float* bias = (which == 0) ? bq : (which == 1) ? bk : bv;
    float bv8[8];
#pragma unroll
    for (int nt = 0; nt < 8; ++nt) bv8[nt] = bias[nt * 16 + li];

    __syncthreads();                      // all waves done reading shW

    unsigned short* stg = shW + wave * 2176;      // wave-private [16][136]
    const int R = lane >> 2, cc4 = lane & 3;
#pragma unroll
    for (int m = 0; m < 4; ++m) {
#pragma unroll
        for (int nt = 0; nt < 8; ++nt)
#pragma unroll
            for (int r = 0; r < 4; ++r)
                stg[(quad * 4 + r) * 136 + nt * 16 + li] = f2bf(acc[m][nt][r] + bv8[nt]);
        __syncthreads();                  // cheap; enforces write->read ordering

        const int node = mbase + m * 16 + R;
        if (node < n_nodes) {
            const u32x4* s = (const u32x4*)(stg + R * 136 + cc4 * 32);
            u32x4 d0 = s[0], d1 = s[1], d2 = s[2], d3 = s[3];
            unsigned short* dp =
                (which == 0) ? (QVb + (size_t)node * 256 + cc4 * 32)
              : (which == 1) ? (Kb  + (size_t)node * 128 + cc4 * 32)
              :                (QVb + (size_t)node * 256 + 128 + cc4 * 32);
            u32x4* d = (u32x4*)dp;
            d[0] = d0; d[1] = d1; d[2] = d2; d[3] = d3;
        }
        __syncthreads();
    }
}

// ---------------------------------------------------------------------------
// scan: phase 1 block sums; phase 2 fused into phase 3.
// ---------------------------------------------------------------------------
__global__ __launch_bounds__(256) void scan1_kernel(
    const int* __restrict__ counts, int* __restrict__ bsums, int n)
{
    __shared__ int lds[256];
    const int i = blockIdx.x * 256 + threadIdx.x;
    lds[threadIdx.x] = (i < n) ? counts[i] : 0;
    __syncthreads();
    for (int off = 128; off > 0; off >>= 1) {
        if (threadIdx.x < off) lds[threadIdx.x] += lds[threadIdx.x + off];
        __syncthreads();
    }
    if (threadIdx.x == 0) bsums[blockIdx.x] = lds[0];
}

__global__ __launch_bounds__(256) void scan3_kernel(
    const int* __restrict__ counts, const int* __restrict__ bsums,
    int* __restrict__ offsets, int n, int n_edges, int nb)
{
    __shared__ int lds[256];
    const int t = threadIdx.x;

    int v = (t < nb) ? bsums[t] : 0;
    lds[t] = v;
    __syncthreads();
    for (int off = 1; off < 256; off <<= 1) {
        const int u = (t >= off) ? lds[t - off] : 0;
        __syncthreads();
        lds[t] += u;
        __syncthreads();
    }
    const int base = (blockIdx.x > 0) ? lds[blockIdx.x - 1] : 0;
    __syncthreads();

    const int i = blockIdx.x * 256 + t;
    const int c = (i < n) ? counts[i] : 0;
    lds[t] = c;
    __syncthreads();
    for (int off = 1; off < 256; off <<= 1) {
        const int u = (t >= off) ? lds[t - off] : 0;
        __syncthreads();
        lds[t] += u;
        __syncthreads();
    }
    if (i < n) offsets[i] = base + lds[t] - c;
    if (blockIdx.x == 0 && t == 0) offsets[n] = n_edges;
}

// ---------------------------------------------------------------------------
// scatter: NO atomics. pos = offsets[dst] + rank[e]; one 32B record per edge
// [src:4 | pad:4 | ebias bf16 x8:16 | pad:8].
// ---------------------------------------------------------------------------
__global__ __launch_bounds__(256) void scatter_kernel(
    const int* __restrict__ el, const int* __restrict__ rank,
    const unsigned int* __restrict__ ebias_e,
    const int* __restrict__ offsets, unsigned int* __restrict__ recs,
    int n_edges)
{
    const int e = blockIdx.x * 256 + threadIdx.x;
    if (e >= n_edges) return;
    const int2 ed = ((const int2*)el)[e];
    const u32x4 eb = *(const u32x4*)(ebias_e + (size_t)e * 4);
    const int pos = offsets[ed.y] + rank[e];

    u32x4 r0, r1;
    r0[0] = (unsigned)ed.x;
    r0[1] = 0;
    r0[2] = eb[0];
    r0[3] = eb[1];
    r1[0] = eb[2];
    r1[1] = eb[3];
    r1[2] = 0; r1[3] = 0;
    u32x4* rp = (u32x4*)(recs + (size_t)pos * 8);
    rp[0] = r0;
    rp[1] = r1;
}

// ---------------------------------------------------------------------------
// aggregate: 2 edges per wave (32 lanes/edge, 4 elems/lane). Unchanged.
// ---------------------------------------------------------------------------
__global__ __launch_bounds__(256) void aggregate_kernel(
    const unsigned short* __restrict__ QVb, const unsigned short* __restrict__ Kb,
    const int* __restrict__ offsets, const unsigned int* __restrict__ recs,
    float* __restrict__ out, int n_nodes)
{
    const int gw   = (blockIdx.x * 256 + threadIdx.x) >> 6;
    const int lane = threadIdx.x & 63;
    const int half = lane >> 5, ln = lane & 31;
    const int node = gw * 2 + half;
    const int h = ln >> 2;
    const bool valid = node < n_nodes;

    int beg = 0, end = 0;
    if (valid) { beg = offsets[node]; end = offsets[node + 1]; }
    const int cnt = end - beg;
    const int mcnt = max(cnt, __shfl_xor(cnt, 32));

    float k0 = 0.f, k1 = 0.f, k2 = 0.f, k3 = 0.f;
    if (valid) {
        const uint2 kp = ((const uint2*)(Kb + (size_t)node * 128))[ln];
        k0 = bflo(kp.x); k1 = bfhi(kp.x); k2 = bflo(kp.y); k3 = bfhi(kp.y);
    }

    float a0 = 0.f, a1 = 0.f, a2 = 0.f, a3 = 0.f;

    uint2 qp = make_uint2(0, 0), vp = make_uint2(0, 0);
    float eb = 0.f;
    if (cnt > 0) {
        const unsigned int* rb = recs + (size_t)beg * 8;
        const int src = (int)rb[0];
        const unsigned int ebp = rb[2 + (h >> 1)];
        eb = (h & 1) ? bfhi(ebp) : bflo(ebp);
        const uint2* r = (const uint2*)(QVb + (size_t)src * 256);
        qp = r[ln];
        vp = r[32 + ln];
    }

    for (int i = 0; i < mcnt; ++i) {
        uint2 nqp = qp, nvp = vp;
        float neb = eb;
        if (i + 1 < cnt) {   // prefetch next edge
            const unsigned int* rb = recs + (size_t)(beg + i + 1) * 8;
            const int ns = (int)rb[0];
            const unsigned int ebp = rb[2 + (h >> 1)];
            neb = (h & 1) ? bfhi(ebp) : bflo(ebp);
            const uint2* r = (const uint2*)(QVb + (size_t)ns * 256);
            nqp = r[ln];
            nvp = r[32 + ln];
        }

        const float q0 = bflo(qp.x), q1 = bfhi(qp.x);
        const float q2 = bflo(qp.y), q3 = bfhi(qp.y);
        float p = fmaf(q0, k0, fmaf(q1, k1, fmaf(q2, k2, q3 * k3)));
        p += __shfl_xor(p, 1);
        p += __shfl_xor(p, 2);
        const float score = fmaf(p, SCALE, eb);

        float mx = score;
        mx = fmaxf(mx, __shfl_xor(mx, 4));
        mx = fmaxf(mx, __shfl_xor(mx, 8));
        mx = fmaxf(mx, __shfl_xor(mx, 16));
        const float ex = __expf(score - mx);
        float den = ex;
        den += __shfl_xor(den, 4);
        den += __shfl_xor(den, 8);
        den += __shfl_xor(den, 16);
        const float w = __fdividef(ex, den);

        if (i < cnt) {
            a0 = fmaf(w, bflo(vp.x), a0);
            a1 = fmaf(w, bfhi(vp.x), a1);
            a2 = fmaf(w, bflo(vp.y), a2);
            a3 = fmaf(w, bfhi(vp.y), a3);
        }
        qp = nqp; vp = nvp; eb = neb;
    }

    if (valid) {
        f32x4 o; o[0] = a0; o[1] = a1; o[2] = a2; o[3] = a3;
        *(((f32x4*)(out + (size_t)node * OUT_DIM)) + ln) = o;
    }
}

// ---------------------------------------------------------------------------
extern "C" void kernel_launch(void* const* d_in, const int* in_sizes, int n_in,
                              void* d_out, int out_size, void* d_ws, size_t ws_size,
                              hipStream_t stream)
{
    const float* X   = (const float*)d_in[0];
    const float* ef  = (const float*)d_in[1];
    const float* Wq  = (const float*)d_in[2];
    const float* bq  = (const float*)d_in[3];
    const float* Wk  = (const float*)d_in[4];
    const float* bk  = (const float*)d_in[5];
    const float* Wv  = (const float*)d_in[6];
    const float* bv  = (const float*)d_in[7];
    const float* We  = (const float*)d_in[8];
    const float* be  = (const float*)d_in[9];
    const int*   el  = (const int*)d_in[10];

    const int n_nodes = in_sizes[0] / IN_DIM;
    const int n_edges = in_sizes[10] / 2;

    char* w = (char*)d_ws;
    auto alloc = [&](size_t bytes) { char* p = w; w += (bytes + 255) & ~(size_t)255; return p; };

    unsigned short* QVb    = (unsigned short*)alloc((size_t)n_nodes * 256 * 2);
    unsigned short* Kb     = (unsigned short*)alloc((size_t)n_nodes * 128 * 2);
    unsigned short* WtB    = (unsigned short*)alloc((size_t)3 * 128 * 128 * 2);
    unsigned int*   recs   = (unsigned int*)alloc((size_t)n_edges * 32);
    unsigned int*   ebias_e= (unsigned int*)alloc((size_t)n_edges * 16);
    int* rank    = (int*)alloc((size_t)n_edges * 4);
    float* WeR   = (float*)alloc(EDGE_DIM * NUM_HEADS * 4);
    float* beR   = (float*)alloc(NUM_HEADS * 4);
    int* counts  = (int*)alloc((size_t)n_nodes * 4);
    int* offsets = (int*)alloc((size_t)(n_nodes + 1) * 4);
    int* bsums   = (int*)alloc(256 * 4);

    // Xb (bf16 X) lifetime ends before scatter writes recs -> alias the buffer.
    unsigned short* Xb = (unsigned short*)recs;

    const int nbz = (n_nodes + 255) / 256;          // 196
    const int nbw = (3 * 128 * 128) / 256;          // 192
    const int nbx = (n_nodes * 16 + 255) / 256;     // 3125
    setup_kernel<<<nbz + nbw + 1 + nbx, 256, 0, stream>>>(
        counts, n_nodes, nbz, Wq, Wk, Wv, WtB, nbw, We, be, WeR, beR, X, Xb);

    const int nbm = (n_nodes + 255) / 256;          // 196 (M_BLOCK = 256)
    const int nbh = (n_edges + 255) / 256;          // 3125
    mega_kernel<<<3 * nbm + nbh, 256, 0, stream>>>(
        Xb, WtB, bq, bk, bv, QVb, Kb, n_nodes, nbm,
        el, counts, rank, ef, WeR, beR, ebias_e, n_edges);

    const int nb = (n_nodes + 255) / 256;           // 196
    scan1_kernel<<<nb, 256, 0, stream>>>(counts, bsums, n_nodes);
    scan3_kernel<<<nb, 256, 0, stream>>>(counts, bsums, offsets, n_nodes, n_edges, nb);

    scatter_kernel<<<nbh, 256, 0, stream>>>(
        el, rank, ebias_e, offsets, recs, n_edges);

    const int nwaves = (n_nodes + 1) / 2;
    aggregate_kernel<<<(nwaves * 64 + 255) / 256, 256, 0, stream>>>(
        QVb, Kb, offsets, recs, (float*)d_out, n_nodes);
}

// Round 3
// 334.571 us; speedup vs baseline: 1.1486x; 1.0024x over previous
//
#include <hip/hip_runtime.h>
#include <math.h>

#define IN_DIM   128
#define OUT_DIM  128
#define EDGE_DIM 32
#define NUM_HEADS 8
#define HEAD_DIM 16
#define SCALE 0.25f
#define CSTRIDE 16   // counts padded: one counter per 64B line

typedef __attribute__((ext_vector_type(8))) short bf16x8;
typedef __attribute__((ext_vector_type(4))) float f32x4;
typedef __attribute__((ext_vector_type(4))) unsigned int u32x4;

__device__ inline unsigned short f2bf(float x) {   // round-to-nearest-even
    unsigned int u = __float_as_uint(x);
    unsigned int r = u + 0x7fff + ((u >> 16) & 1);
    return (unsigned short)(r >> 16);
}
__device__ inline float bflo(unsigned int u) { return __uint_as_float(u << 16); }
__device__ inline float bfhi(unsigned int u) { return __uint_as_float(u & 0xffff0000u); }

// ---------------------------------------------------------------------------
// setup: [zero padded counts] + [W^T bf16] + [We head-sum reduce] + [X -> bf16]
// ---------------------------------------------------------------------------
__global__ __launch_bounds__(256) void setup_kernel(
    int* __restrict__ counts, int n_nodes, int nbz,
    const float* __restrict__ Wq, const float* __restrict__ Wk,
    const float* __restrict__ Wv, unsigned short* __restrict__ WtB, int nbw,
    const float* __restrict__ We, const float* __restrict__ be,
    float* __restrict__ WeR, float* __restrict__ beR,
    const float* __restrict__ X, unsigned short* __restrict__ Xb)
{
    const int bx = blockIdx.x;
    const int t  = threadIdx.x;
    if (bx < nbz) {                                   // zero counts (padded slots)
        const int i = bx * 256 + t;
        if (i < n_nodes) counts[i << 4] = 0;
    } else if (bx < nbz + nbw) {                      // W[k][n] -> WtB[mat][n][k]
        const int idx = (bx - nbz) * 256 + t;
        const int mat = idx >> 14;
        const int rem = idx & 16383;
        const int n = rem >> 7, k = rem & 127;
        const float* W = (mat == 0) ? Wq : (mat == 1) ? Wk : Wv;
        WtB[mat * 16384 + n * 128 + k] = f2bf(W[k * 128 + n]);
    } else if (bx == nbz + nbw) {                     // We reduce
        const int k = t >> 3, h = t & 7;
        float s = 0.f;
#pragma unroll
        for (int d = 0; d < HEAD_DIM; ++d) s += We[k * OUT_DIM + h * HEAD_DIM + d];
        WeR[k * NUM_HEADS + h] = s;
        if (t < NUM_HEADS) {
            float sb = 0.f;
#pragma unroll
            for (int d = 0; d < HEAD_DIM; ++d) sb += be[t * HEAD_DIM + d];
            beR[t] = sb;
        }
    } else {                                          // X f32 -> bf16 (8/thread)
        const int i = (bx - (nbz + nbw + 1)) * 256 + t;
        if (i < n_nodes * 16) {
            const f32x4* xr = (const f32x4*)(X + (size_t)i * 8);
            const f32x4 x0 = xr[0], x1 = xr[1];
            u32x4 p;
            p[0] = (unsigned)f2bf(x0[0]) | ((unsigned)f2bf(x0[1]) << 16);
            p[1] = (unsigned)f2bf(x0[2]) | ((unsigned)f2bf(x0[3]) << 16);
            p[2] = (unsigned)f2bf(x1[0]) | ((unsigned)f2bf(x1[1]) << 16);
            p[3] = (unsigned)f2bf(x1[2]) | ((unsigned)f2bf(x1[3]) << 16);
            *(u32x4*)(Xb + (size_t)i * 8) = p;
        }
    }
}

// ---------------------------------------------------------------------------
// edge_kernel: hist atomic (padded counters, rank) + ef GEMV (uniform scalar
// weights -> SGPRs) + ebias write. No LDS -> max occupancy for atomic latency.
// ---------------------------------------------------------------------------
__global__ __launch_bounds__(256) void edge_kernel(
    const int* __restrict__ el, int* __restrict__ counts, int* __restrict__ rank,
    const float* __restrict__ ef, const float* __restrict__ WeR,
    const float* __restrict__ beR, unsigned int* __restrict__ ebias_e,
    int n_edges)
{
    const int e = blockIdx.x * 256 + threadIdx.x;
    if (e >= n_edges) return;
    const int2 ed = ((const int2*)el)[e];
    rank[e] = atomicAdd(&counts[ed.y << 4], 1);

    float acc[NUM_HEADS];
#pragma unroll
    for (int h = 0; h < NUM_HEADS; ++h) acc[h] = beR[h];   // uniform -> s_load

    const f32x4* efr = (const f32x4*)(ef + (size_t)e * EDGE_DIM);
#pragma unroll
    for (int kk = 0; kk < 8; ++kk) {
        const f32x4 f = efr[kk];
#pragma unroll
        for (int c = 0; c < 4; ++c) {
            const float* wr = WeR + (kk * 4 + c) * NUM_HEADS;  // uniform
#pragma unroll
            for (int h = 0; h < NUM_HEADS; ++h)
                acc[h] = fmaf(f[c], wr[h], acc[h]);
        }
    }
    u32x4 pk;
    pk[0] = (unsigned)f2bf(acc[0]) | ((unsigned)f2bf(acc[1]) << 16);
    pk[1] = (unsigned)f2bf(acc[2]) | ((unsigned)f2bf(acc[3]) << 16);
    pk[2] = (unsigned)f2bf(acc[4]) | ((unsigned)f2bf(acc[5]) << 16);
    pk[3] = (unsigned)f2bf(acc[6]) | ((unsigned)f2bf(acc[7]) << 16);
    *(u32x4*)(ebias_e + (size_t)e * 4) = pk;
}

// ---------------------------------------------------------------------------
// qkv_kernel: one `which` per block, W^T staged in LDS (XOR-swizzled),
// M_BLOCK=256 rows (64 rows/wave, 128 MFMA/wave).
// ---------------------------------------------------------------------------
__global__ __launch_bounds__(256) void qkv_kernel(
    const unsigned short* __restrict__ Xb, const unsigned short* __restrict__ WtB,
    const float* __restrict__ bq, const float* __restrict__ bk,
    const float* __restrict__ bv,
    unsigned short* __restrict__ QVb, unsigned short* __restrict__ Kb,
    int n_nodes, int nbm)
{
    __shared__ unsigned short shW[16384];   // 32KB: W^T (swizzled), reused as stg
    const int bx = blockIdx.x;
    const int t  = threadIdx.x;

    const int which = bx / nbm;
    const int mb    = bx - which * nbm;
    const unsigned short* Wg = WtB + which * 16384;

    // stage W^T -> LDS, 16B chunks, XOR-swizzle row-stride-256B bank conflict away
#pragma unroll
    for (int kk = 0; kk < 8; ++kk) {
        const int c = kk * 256 + t;                 // 2048 chunks of 16B
        const u32x4 v = ((const u32x4*)Wg)[c];
        const int row = c >> 4;                     // 16 chunks per 256B row
        const int bir = (c & 15) << 4;
        *(u32x4*)((char*)shW + row * 256 + (bir ^ ((row & 7) << 4))) = v;
    }
    __syncthreads();

    const int wave = t >> 6, lane = t & 63;
    const int quad = lane >> 4, li = lane & 15;
    const int mbase = mb * 256 + wave * 64;

    int mrow[4];
#pragma unroll
    for (int m = 0; m < 4; ++m) {
        const int r_ = mbase + m * 16 + li;
        mrow[m] = (r_ < n_nodes) ? r_ : (n_nodes - 1);
    }

    f32x4 acc[4][8];
#pragma unroll
    for (int m = 0; m < 4; ++m)
#pragma unroll
        for (int nt = 0; nt < 8; ++nt) acc[m][nt] = (f32x4){0.f, 0.f, 0.f, 0.f};

#pragma unroll
    for (int ks = 0; ks < 4; ++ks) {
        bf16x8 a[4];
#pragma unroll
        for (int m = 0; m < 4; ++m)
            a[m] = *(const bf16x8*)(Xb + (size_t)mrow[m] * 128 + ks * 32 + quad * 8);
#pragma unroll
        for (int nt = 0; nt < 8; ++nt) {
            const int row = nt * 16 + li;
            const bf16x8 b = *(const bf16x8*)((const char*)shW + row * 256 +
                                ((ks * 64 + quad * 16) ^ ((row & 7) << 4)));
#pragma unroll
            for (int m = 0; m < 4; ++m)
                acc[m][nt] = __builtin_amdgcn_mfma_f32_16x16x32_bf16(a[m], b, acc[m][nt], 0, 0, 0);
        }
    }

    const float* bias = (which == 0) ? bq : (which == 1) ? bk : bv;
    float bv8[8];
#pragma unroll
    for (int nt = 0; nt < 8; ++nt) bv8[nt] = bias[nt * 16 + li];

    __syncthreads();                      // all waves done reading shW

    unsigned short* stg = shW + wave * 2176;      // wave-private [16][136]
    const int R = lane >> 2, cc4 = lane & 3;
#pragma unroll
    for (int m = 0; m < 4; ++m) {
#pragma unroll
        for (int nt = 0; nt < 8; ++nt)
#pragma unroll
            for (int r = 0; r < 4; ++r)
                stg[(quad * 4 + r) * 136 + nt * 16 + li] = f2bf(acc[m][nt][r] + bv8[nt]);
        __syncthreads();

        const int node = mbase + m * 16 + R;
        if (node < n_nodes) {
            const u32x4* s = (const u32x4*)(stg + R * 136 + cc4 * 32);
            u32x4 d0 = s[0], d1 = s[1], d2 = s[2], d3 = s[3];
            unsigned short* dp =
                (which == 0) ? (QVb + (size_t)node * 256 + cc4 * 32)
              : (which == 1) ? (Kb  + (size_t)node * 128 + cc4 * 32)
              :                (QVb + (size_t)node * 256 + 128 + cc4 * 32);
            u32x4* d = (u32x4*)dp;
            d[0] = d0; d[1] = d1; d[2] = d2; d[3] = d3;
        }
        __syncthreads();
    }
}

// ---------------------------------------------------------------------------
// scan: phase 1 block sums; phase 2 fused into phase 3. counts are padded.
// ---------------------------------------------------------------------------
__global__ __launch_bounds__(256) void scan1_kernel(
    const int* __restrict__ counts, int* __restrict__ bsums, int n)
{
    __shared__ int lds[256];
    const int i = blockIdx.x * 256 + threadIdx.x;
    lds[threadIdx.x] = (i < n) ? counts[i << 4] : 0;
    __syncthreads();
    for (int off = 128; off > 0; off >>= 1) {
        if (threadIdx.x < off) lds[threadIdx.x] += lds[threadIdx.x + off];
        __syncthreads();
    }
    if (threadIdx.x == 0) bsums[blockIdx.x] = lds[0];
}

__global__ __launch_bounds__(256) void scan3_kernel(
    const int* __restrict__ counts, const int* __restrict__ bsums,
    int* __restrict__ offsets, int n, int n_edges, int nb)
{
    __shared__ int lds[256];
    const int t = threadIdx.x;

    int v = (t < nb) ? bsums[t] : 0;
    lds[t] = v;
    __syncthreads();
    for (int off = 1; off < 256; off <<= 1) {
        const int u = (t >= off) ? lds[t - off] : 0;
        __syncthreads();
        lds[t] += u;
        __syncthreads();
    }
    const int base = (blockIdx.x > 0) ? lds[blockIdx.x - 1] : 0;
    __syncthreads();

    const int i = blockIdx.x * 256 + t;
    const int c = (i < n) ? counts[i << 4] : 0;
    lds[t] = c;
    __syncthreads();
    for (int off = 1; off < 256; off <<= 1) {
        const int u = (t >= off) ? lds[t - off] : 0;
        __syncthreads();
        lds[t] += u;
        __syncthreads();
    }
    if (i < n) offsets[i] = base + lds[t] - c;
    if (blockIdx.x == 0 && t == 0) offsets[n] = n_edges;
}

// ---------------------------------------------------------------------------
// scatter: NO atomics. pos = offsets[dst] + rank[e]; one 32B record per edge
// [src:4 | pad:4 | ebias bf16 x8:16 | pad:8].
// ---------------------------------------------------------------------------
__global__ __launch_bounds__(256) void scatter_kernel(
    const int* __restrict__ el, const int* __restrict__ rank,
    const unsigned int* __restrict__ ebias_e,
    const int* __restrict__ offsets, unsigned int* __restrict__ recs,
    int n_edges)
{
    const int e = blockIdx.x * 256 + threadIdx.x;
    if (e >= n_edges) return;
    const int2 ed = ((const int2*)el)[e];
    const u32x4 eb = *(const u32x4*)(ebias_e + (size_t)e * 4);
    const int pos = offsets[ed.y] + rank[e];

    u32x4 r0, r1;
    r0[0] = (unsigned)ed.x;
    r0[1] = 0;
    r0[2] = eb[0];
    r0[3] = eb[1];
    r1[0] = eb[2];
    r1[1] = eb[3];
    r1[2] = 0; r1[3] = 0;
    u32x4* rp = (u32x4*)(recs + (size_t)pos * 8);
    rp[0] = r0;
    rp[1] = r1;
}

// ---------------------------------------------------------------------------
// aggregate: 2 edges per wave (32 lanes/edge, 4 elems/lane). Unchanged.
// ---------------------------------------------------------------------------
__global__ __launch_bounds__(256) void aggregate_kernel(
    const unsigned short* __restrict__ QVb, const unsigned short* __restrict__ Kb,
    const int* __restrict__ offsets, const unsigned int* __restrict__ recs,
    float* __restrict__ out, int n_nodes)
{
    const int gw   = (blockIdx.x * 256 + threadIdx.x) >> 6;
    const int lane = threadIdx.x & 63;
    const int half = lane >> 5, ln = lane & 31;
    const int node = gw * 2 + half;
    const int h = ln >> 2;
    const bool valid = node < n_nodes;

    int beg = 0, end = 0;
    if (valid) { beg = offsets[node]; end = offsets[node + 1]; }
    const int cnt = end - beg;
    const int mcnt = max(cnt, __shfl_xor(cnt, 32));

    float k0 = 0.f, k1 = 0.f, k2 = 0.f, k3 = 0.f;
    if (valid) {
        const uint2 kp = ((const uint2*)(Kb + (size_t)node * 128))[ln];
        k0 = bflo(kp.x); k1 = bfhi(kp.x); k2 = bflo(kp.y); k3 = bfhi(kp.y);
    }

    float a0 = 0.f, a1 = 0.f, a2 = 0.f, a3 = 0.f;

    uint2 qp = make_uint2(0, 0), vp = make_uint2(0, 0);
    float eb = 0.f;
    if (cnt > 0) {
        const unsigned int* rb = recs + (size_t)beg * 8;
        const int src = (int)rb[0];
        const unsigned int ebp = rb[2 + (h >> 1)];
        eb = (h & 1) ? bfhi(ebp) : bflo(ebp);
        const uint2* r = (const uint2*)(QVb + (size_t)src * 256);
        qp = r[ln];
        vp = r[32 + ln];
    }

    for (int i = 0; i < mcnt; ++i) {
        uint2 nqp = qp, nvp = vp;
        float neb = eb;
        if (i + 1 < cnt) {   // prefetch next edge
            const unsigned int* rb = recs + (size_t)(beg + i + 1) * 8;
            const int ns = (int)rb[0];
            const unsigned int ebp = rb[2 + (h >> 1)];
            neb = (h & 1) ? bfhi(ebp) : bflo(ebp);
            const uint2* r = (const uint2*)(QVb + (size_t)ns * 256);
            nqp = r[ln];
            nvp = r[32 + ln];
        }

        const float q0 = bflo(qp.x), q1 = bfhi(qp.x);
        const float q2 = bflo(qp.y), q3 = bfhi(qp.y);
        float p = fmaf(q0, k0, fmaf(q1, k1, fmaf(q2, k2, q3 * k3)));
        p += __shfl_xor(p, 1);
        p += __shfl_xor(p, 2);
        const float score = fmaf(p, SCALE, eb);

        float mx = score;
        mx = fmaxf(mx, __shfl_xor(mx, 4));
        mx = fmaxf(mx, __shfl_xor(mx, 8));
        mx = fmaxf(mx, __shfl_xor(mx, 16));
        const float ex = __expf(score - mx);
        float den = ex;
        den += __shfl_xor(den, 4);
        den += __shfl_xor(den, 8);
        den += __shfl_xor(den, 16);
        const float w = __fdividef(ex, den);

        if (i < cnt) {
            a0 = fmaf(w, bflo(vp.x), a0);
            a1 = fmaf(w, bfhi(vp.x), a1);
            a2 = fmaf(w, bflo(vp.y), a2);
            a3 = fmaf(w, bfhi(vp.y), a3);
        }
        qp = nqp; vp = nvp; eb = neb;
    }

    if (valid) {
        f32x4 o; o[0] = a0; o[1] = a1; o[2] = a2; o[3] = a3;
        *(((f32x4*)(out + (size_t)node * OUT_DIM)) + ln) = o;
    }
}

// ---------------------------------------------------------------------------
extern "C" void kernel_launch(void* const* d_in, const int* in_sizes, int n_in,
                              void* d_out, int out_size, void* d_ws, size_t ws_size,
                              hipStream_t stream)
{
    const float* X   = (const float*)d_in[0];
    const float* ef  = (const float*)d_in[1];
    const float* Wq  = (const float*)d_in[2];
    const float* bq  = (const float*)d_in[3];
    const float* Wk  = (const float*)d_in[4];
    const float* bk  = (const float*)d_in[5];
    const float* Wv  = (const float*)d_in[6];
    const float* bv  = (const float*)d_in[7];
    const float* We  = (const float*)d_in[8];
    const float* be  = (const float*)d_in[9];
    const int*   el  = (const int*)d_in[10];

    const int n_nodes = in_sizes[0] / IN_DIM;
    const int n_edges = in_sizes[10] / 2;

    char* w = (char*)d_ws;
    auto alloc = [&](size_t bytes) { char* p = w; w += (bytes + 255) & ~(size_t)255; return p; };

    unsigned short* QVb    = (unsigned short*)alloc((size_t)n_nodes * 256 * 2);
    unsigned short* Kb     = (unsigned short*)alloc((size_t)n_nodes * 128 * 2);
    unsigned short* WtB    = (unsigned short*)alloc((size_t)3 * 128 * 128 * 2);
    unsigned int*   recs   = (unsigned int*)alloc((size_t)n_edges * 32);
    unsigned int*   ebias_e= (unsigned int*)alloc((size_t)n_edges * 16);
    int* rank    = (int*)alloc((size_t)n_edges * 4);
    float* WeR   = (float*)alloc(EDGE_DIM * NUM_HEADS * 4);
    float* beR   = (float*)alloc(NUM_HEADS * 4);
    int* counts  = (int*)alloc((size_t)n_nodes * CSTRIDE * 4);   // padded 64B/ctr
    int* offsets = (int*)alloc((size_t)(n_nodes + 1) * 4);
    int* bsums   = (int*)alloc(256 * 4);

    // Xb (bf16 X) lifetime ends before scatter writes recs -> alias the buffer.
    unsigned short* Xb = (unsigned short*)recs;

    const int nbz = (n_nodes + 255) / 256;          // 196
    const int nbw = (3 * 128 * 128) / 256;          // 192
    const int nbx = (n_nodes * 16 + 255) / 256;     // 3125
    setup_kernel<<<nbz + nbw + 1 + nbx, 256, 0, stream>>>(
        counts, n_nodes, nbz, Wq, Wk, Wv, WtB, nbw, We, be, WeR, beR, X, Xb);

    const int nbh = (n_edges + 255) / 256;          // 3125
    edge_kernel<<<nbh, 256, 0, stream>>>(
        el, counts, rank, ef, WeR, beR, ebias_e, n_edges);

    const int nbm = (n_nodes + 255) / 256;          // 196 (M_BLOCK = 256)
    qkv_kernel<<<3 * nbm, 256, 0, stream>>>(
        Xb, WtB, bq, bk, bv, QVb, Kb, n_nodes, nbm);

    const int nb = (n_nodes + 255) / 256;           // 196
    scan1_kernel<<<nb, 256, 0, stream>>>(counts, bsums, n_nodes);
    scan3_kernel<<<nb, 256, 0, stream>>>(counts, bsums, offsets, n_nodes, n_edges, nb);

    scatter_kernel<<<nbh, 256, 0, stream>>>(
        el, rank, ebias_e, offsets, recs, n_edges);

    const int nwaves = (n_nodes + 1) / 2;
    aggregate_kernel<<<(nwaves * 64 + 255) / 256, 256, 0, stream>>>(
        QVb, Kb, offsets, recs, (float*)d_out, n_nodes);
}

// Round 4
// 322.828 us; speedup vs baseline: 1.1904x; 1.0364x over previous
//
#include <hip/hip_runtime.h>
#include <math.h>

#define IN_DIM   128
#define OUT_DIM  128
#define EDGE_DIM 32
#define NUM_HEADS 8
#define HEAD_DIM 16
#define SCALE 0.25f
#define CSTRIDE 16   // counts padded: one counter per 64B line

typedef __attribute__((ext_vector_type(8))) short bf16x8;
typedef __attribute__((ext_vector_type(4))) float f32x4;
typedef __attribute__((ext_vector_type(4))) unsigned int u32x4;

__device__ inline unsigned short f2bf(float x) {   // round-to-nearest-even
    unsigned int u = __float_as_uint(x);
    unsigned int r = u + 0x7fff + ((u >> 16) & 1);
    return (unsigned short)(r >> 16);
}
__device__ inline float bflo(unsigned int u) { return __uint_as_float(u << 16); }
__device__ inline float bfhi(unsigned int u) { return __uint_as_float(u & 0xffff0000u); }

// ---------------------------------------------------------------------------
// setup: [zero padded counts] + [W^T bf16] + [We head-sum reduce] + [X -> bf16]
// ---------------------------------------------------------------------------
__global__ __launch_bounds__(256) void setup_kernel(
    int* __restrict__ counts, int n_nodes, int nbz,
    const float* __restrict__ Wq, const float* __restrict__ Wk,
    const float* __restrict__ Wv, unsigned short* __restrict__ WtB, int nbw,
    const float* __restrict__ We, const float* __restrict__ be,
    float* __restrict__ WeR, float* __restrict__ beR,
    const float* __restrict__ X, unsigned short* __restrict__ Xb)
{
    const int bx = blockIdx.x;
    const int t  = threadIdx.x;
    if (bx < nbz) {                                   // zero counts (padded slots)
        const int i = bx * 256 + t;
        if (i < n_nodes) counts[i << 4] = 0;
    } else if (bx < nbz + nbw) {                      // W[k][n] -> WtB[mat][n][k]
        const int idx = (bx - nbz) * 256 + t;
        const int mat = idx >> 14;
        const int rem = idx & 16383;
        const int n = rem >> 7, k = rem & 127;
        const float* W = (mat == 0) ? Wq : (mat == 1) ? Wk : Wv;
        WtB[mat * 16384 + n * 128 + k] = f2bf(W[k * 128 + n]);
    } else if (bx == nbz + nbw) {                     // We reduce
        const int k = t >> 3, h = t & 7;
        float s = 0.f;
#pragma unroll
        for (int d = 0; d < HEAD_DIM; ++d) s += We[k * OUT_DIM + h * HEAD_DIM + d];
        WeR[k * NUM_HEADS + h] = s;
        if (t < NUM_HEADS) {
            float sb = 0.f;
#pragma unroll
            for (int d = 0; d < HEAD_DIM; ++d) sb += be[t * HEAD_DIM + d];
            beR[t] = sb;
        }
    } else {                                          // X f32 -> bf16 (8/thread)
        const int i = (bx - (nbz + nbw + 1)) * 256 + t;
        if (i < n_nodes * 16) {
            const f32x4* xr = (const f32x4*)(X + (size_t)i * 8);
            const f32x4 x0 = xr[0], x1 = xr[1];
            u32x4 p;
            p[0] = (unsigned)f2bf(x0[0]) | ((unsigned)f2bf(x0[1]) << 16);
            p[1] = (unsigned)f2bf(x0[2]) | ((unsigned)f2bf(x0[3]) << 16);
            p[2] = (unsigned)f2bf(x1[0]) | ((unsigned)f2bf(x1[1]) << 16);
            p[3] = (unsigned)f2bf(x1[2]) | ((unsigned)f2bf(x1[3]) << 16);
            *(u32x4*)(Xb + (size_t)i * 8) = p;
        }
    }
}

// ---------------------------------------------------------------------------
// edge_kernel: hist atomic (padded counters, rank) + ef GEMV (uniform scalar
// weights -> SGPRs) + ebias write. No LDS -> max occupancy for atomic latency.
// ---------------------------------------------------------------------------
__global__ __launch_bounds__(256) void edge_kernel(
    const int* __restrict__ el, int* __restrict__ counts, int* __restrict__ rank,
    const float* __restrict__ ef, const float* __restrict__ WeR,
    const float* __restrict__ beR, unsigned int* __restrict__ ebias_e,
    int n_edges)
{
    const int e = blockIdx.x * 256 + threadIdx.x;
    if (e >= n_edges) return;
    const int2 ed = ((const int2*)el)[e];
    rank[e] = atomicAdd(&counts[ed.y << 4], 1);

    float acc[NUM_HEADS];
#pragma unroll
    for (int h = 0; h < NUM_HEADS; ++h) acc[h] = beR[h];   // uniform -> s_load

    const f32x4* efr = (const f32x4*)(ef + (size_t)e * EDGE_DIM);
#pragma unroll
    for (int kk = 0; kk < 8; ++kk) {
        const f32x4 f = efr[kk];
#pragma unroll
        for (int c = 0; c < 4; ++c) {
            const float* wr = WeR + (kk * 4 + c) * NUM_HEADS;  // uniform
#pragma unroll
            for (int h = 0; h < NUM_HEADS; ++h)
                acc[h] = fmaf(f[c], wr[h], acc[h]);
        }
    }
    u32x4 pk;
    pk[0] = (unsigned)f2bf(acc[0]) | ((unsigned)f2bf(acc[1]) << 16);
    pk[1] = (unsigned)f2bf(acc[2]) | ((unsigned)f2bf(acc[3]) << 16);
    pk[2] = (unsigned)f2bf(acc[4]) | ((unsigned)f2bf(acc[5]) << 16);
    pk[3] = (unsigned)f2bf(acc[6]) | ((unsigned)f2bf(acc[7]) << 16);
    *(u32x4*)(ebias_e + (size_t)e * 4) = pk;
}

// ---------------------------------------------------------------------------
// qkv_kernel: one `which` per block, W^T staged in LDS (XOR-swizzled),
// M_BLOCK=256 rows (64 rows/wave, 128 MFMA/wave).
// ---------------------------------------------------------------------------
__global__ __launch_bounds__(256) void qkv_kernel(
    const unsigned short* __restrict__ Xb, const unsigned short* __restrict__ WtB,
    const float* __restrict__ bq, const float* __restrict__ bk,
    const float* __restrict__ bv,
    unsigned short* __restrict__ QVb, unsigned short* __restrict__ Kb,
    int n_nodes, int nbm)
{
    __shared__ unsigned short shW[16384];   // 32KB: W^T (swizzled), reused as stg
    const int bx = blockIdx.x;
    const int t  = threadIdx.x;

    const int which = bx / nbm;
    const int mb    = bx - which * nbm;
    const unsigned short* Wg = WtB + which * 16384;

    // stage W^T -> LDS, 16B chunks, XOR-swizzle row-stride-256B bank conflict away
#pragma unroll
    for (int kk = 0; kk < 8; ++kk) {
        const int c = kk * 256 + t;                 // 2048 chunks of 16B
        const u32x4 v = ((const u32x4*)Wg)[c];
        const int row = c >> 4;                     // 16 chunks per 256B row
        const int bir = (c & 15) << 4;
        *(u32x4*)((char*)shW + row * 256 + (bir ^ ((row & 7) << 4))) = v;
    }
    __syncthreads();

    const int wave = t >> 6, lane = t & 63;
    const int quad = lane >> 4, li = lane & 15;
    const int mbase = mb * 256 + wave * 64;

    int mrow[4];
#pragma unroll
    for (int m = 0; m < 4; ++m) {
        const int r_ = mbase + m * 16 + li;
        mrow[m] = (r_ < n_nodes) ? r_ : (n_nodes - 1);
    }

    f32x4 acc[4][8];
#pragma unroll
    for (int m = 0; m < 4; ++m)
#pragma unroll
        for (int nt = 0; nt < 8; ++nt) acc[m][nt] = (f32x4){0.f, 0.f, 0.f, 0.f};

#pragma unroll
    for (int ks = 0; ks < 4; ++ks) {
        bf16x8 a[4];
#pragma unroll
        for (int m = 0; m < 4; ++m)
            a[m] = *(const bf16x8*)(Xb + (size_t)mrow[m] * 128 + ks * 32 + quad * 8);
#pragma unroll
        for (int nt = 0; nt < 8; ++nt) {
            const int row = nt * 16 + li;
            const bf16x8 b = *(const bf16x8*)((const char*)shW + row * 256 +
                                ((ks * 64 + quad * 16) ^ ((row & 7) << 4)));
#pragma unroll
            for (int m = 0; m < 4; ++m)
                acc[m][nt] = __builtin_amdgcn_mfma_f32_16x16x32_bf16(a[m], b, acc[m][nt], 0, 0, 0);
        }
    }

    const float* bias = (which == 0) ? bq : (which == 1) ? bk : bv;
    float bv8[8];
#pragma unroll
    for (int nt = 0; nt < 8; ++nt) bv8[nt] = bias[nt * 16 + li];

    __syncthreads();                      // all waves done reading shW

    unsigned short* stg = shW + wave * 2176;      // wave-private [16][136]
    const int R = lane >> 2, cc4 = lane & 3;
#pragma unroll
    for (int m = 0; m < 4; ++m) {
#pragma unroll
        for (int nt = 0; nt < 8; ++nt)
#pragma unroll
            for (int r = 0; r < 4; ++r)
                stg[(quad * 4 + r) * 136 + nt * 16 + li] = f2bf(acc[m][nt][r] + bv8[nt]);
        __syncthreads();

        const int node = mbase + m * 16 + R;
        if (node < n_nodes) {
            const u32x4* s = (const u32x4*)(stg + R * 136 + cc4 * 32);
            u32x4 d0 = s[0], d1 = s[1], d2 = s[2], d3 = s[3];
            unsigned short* dp =
                (which == 0) ? (QVb + (size_t)node * 256 + cc4 * 32)
              : (which == 1) ? (Kb  + (size_t)node * 128 + cc4 * 32)
              :                (QVb + (size_t)node * 256 + 128 + cc4 * 32);
            u32x4* d = (u32x4*)dp;
            d[0] = d0; d[1] = d1; d[2] = d2; d[3] = d3;
        }
        __syncthreads();
    }
}

// ---------------------------------------------------------------------------
// scan: phase 1 block sums; phase 2 fused into phase 3. counts are padded.
// ---------------------------------------------------------------------------
__global__ __launch_bounds__(256) void scan1_kernel(
    const int* __restrict__ counts, int* __restrict__ bsums, int n)
{
    __shared__ int lds[256];
    const int i = blockIdx.x * 256 + threadIdx.x;
    lds[threadIdx.x] = (i < n) ? counts[i << 4] : 0;
    __syncthreads();
    for (int off = 128; off > 0; off >>= 1) {
        if (threadIdx.x < off) lds[threadIdx.x] += lds[threadIdx.x + off];
        __syncthreads();
    }
    if (threadIdx.x == 0) bsums[blockIdx.x] = lds[0];
}

__global__ __launch_bounds__(256) void scan3_kernel(
    const int* __restrict__ counts, const int* __restrict__ bsums,
    int* __restrict__ offsets, int n, int n_edges, int nb)
{
    __shared__ int lds[256];
    const int t = threadIdx.x;

    int v = (t < nb) ? bsums[t] : 0;
    lds[t] = v;
    __syncthreads();
    for (int off = 1; off < 256; off <<= 1) {
        const int u = (t >= off) ? lds[t - off] : 0;
        __syncthreads();
        lds[t] += u;
        __syncthreads();
    }
    const int base = (blockIdx.x > 0) ? lds[blockIdx.x - 1] : 0;
    __syncthreads();

    const int i = blockIdx.x * 256 + t;
    const int c = (i < n) ? counts[i << 4] : 0;
    lds[t] = c;
    __syncthreads();
    for (int off = 1; off < 256; off <<= 1) {
        const int u = (t >= off) ? lds[t - off] : 0;
        __syncthreads();
        lds[t] += u;
        __syncthreads();
    }
    if (i < n) offsets[i] = base + lds[t] - c;
    if (blockIdx.x == 0 && t == 0) offsets[n] = n_edges;
}

// ---------------------------------------------------------------------------
// scatter: NO atomics. pos = offsets[dst] + rank[e]; one 32B record per edge
// [src:4 | pad:4 | ebias bf16 x8:16 | pad:8].
// ---------------------------------------------------------------------------
__global__ __launch_bounds__(256) void scatter_kernel(
    const int* __restrict__ el, const int* __restrict__ rank,
    const unsigned int* __restrict__ ebias_e,
    const int* __restrict__ offsets, unsigned int* __restrict__ recs,
    int n_edges)
{
    const int e = blockIdx.x * 256 + threadIdx.x;
    if (e >= n_edges) return;
    const int2 ed = ((const int2*)el)[e];
    const u32x4 eb = *(const u32x4*)(ebias_e + (size_t)e * 4);
    const int pos = offsets[ed.y] + rank[e];

    u32x4 r0, r1;
    r0[0] = (unsigned)ed.x;
    r0[1] = 0;
    r0[2] = eb[0];
    r0[3] = eb[1];
    r1[0] = eb[2];
    r1[1] = eb[3];
    r1[2] = 0; r1[3] = 0;
    u32x4* rp = (u32x4*)(recs + (size_t)pos * 8);
    rp[0] = r0;
    rp[1] = r1;
}

// ---------------------------------------------------------------------------
// aggregate v2: one node per wave; 8 edges in flight; lane = (group g, head h).
// Lane computes its head's 16-dim dot; softmax = 6 shuffles within the 8-lane
// group; V accumulated per-head in registers. 2-deep software pipeline:
// rec(src,eb) fetched 2 iters ahead so Q/V loads issue a full iteration early.
// Epilogue: butterfly reduce across groups (xor 8/16/32) + coalesced 512B store.
// ---------------------------------------------------------------------------
__global__ __launch_bounds__(256) void aggregate_kernel(
    const unsigned short* __restrict__ QVb, const unsigned short* __restrict__ Kb,
    const int* __restrict__ offsets, const unsigned int* __restrict__ recs,
    float* __restrict__ out, int n_nodes)
{
    const int wave = threadIdx.x >> 6;
    const int lane = threadIdx.x & 63;
    const int node = blockIdx.x * 4 + wave;
    if (node >= n_nodes) return;
    const int g = lane >> 3;      // edge slot within the 8-wide flight group
    const int h = lane & 7;       // head

    const int beg = offsets[node];
    const int end = offsets[node + 1];
    const int cnt = end - beg;

    // K slice for this head (broadcast across the 8 groups): 16 bf16 = 32B
    float kf[16];
    {
        const u32x4* kp = (const u32x4*)(Kb + (size_t)node * 128 + h * 16);
        const u32x4 ka = kp[0], kb_ = kp[1];
#pragma unroll
        for (int j = 0; j < 4; ++j) { kf[j * 2] = bflo(ka[j]);  kf[j * 2 + 1] = bfhi(ka[j]); }
#pragma unroll
        for (int j = 0; j < 4; ++j) { kf[8 + j * 2] = bflo(kb_[j]); kf[8 + j * 2 + 1] = bfhi(kb_[j]); }
    }

    float acc[16];
#pragma unroll
    for (int d = 0; d < 16; ++d) acc[d] = 0.f;

    if (cnt > 0) {
        const int last = end - 1;
        const int ebd  = 2 + (h >> 1);           // rec dword holding this head's eb

        // ---- pipeline prologue ----
        int s0 = beg + g;            if (s0 > last) s0 = last;
        unsigned int src_c = recs[(size_t)s0 * 8];
        unsigned int ebw_c = recs[(size_t)s0 * 8 + ebd];
        u32x4 qa, qb, va, vb;
        {
            const u32x4* qp = (const u32x4*)(QVb + (size_t)src_c * 256 + h * 16);
            qa = qp[0]; qb = qp[1];
            const u32x4* vp = (const u32x4*)(QVb + (size_t)src_c * 256 + 128 + h * 16);
            va = vp[0]; vb = vp[1];
        }
        int s1 = beg + 8 + g;        if (s1 > last) s1 = last;
        unsigned int src_n = recs[(size_t)s1 * 8];
        unsigned int ebw_n = recs[(size_t)s1 * 8 + ebd];

        for (int i = 0; i < cnt; i += 8) {
            // issue rec loads for i+16
            int s2 = beg + i + 16 + g;  if (s2 > last) s2 = last;
            const unsigned int src_f = recs[(size_t)s2 * 8];
            const unsigned int ebw_f = recs[(size_t)s2 * 8 + ebd];
            // issue Q/V loads for the NEXT edge (src known since last iter)
            u32x4 qan, qbn, van, vbn;
            {
                const u32x4* qp = (const u32x4*)(QVb + (size_t)src_n * 256 + h * 16);
                qan = qp[0]; qbn = qp[1];
                const u32x4* vp = (const u32x4*)(QVb + (size_t)src_n * 256 + 128 + h * 16);
                van = vp[0]; vbn = vp[1];
            }

            // ---- compute with current edge ----
            const float eb = (h & 1) ? bfhi(ebw_c) : bflo(ebw_c);
            float p = 0.f;
#pragma unroll
            for (int j = 0; j < 4; ++j) {
                p = fmaf(bflo(qa[j]), kf[j * 2],     p);
                p = fmaf(bfhi(qa[j]), kf[j * 2 + 1], p);
            }
#pragma unroll
            for (int j = 0; j < 4; ++j) {
                p = fmaf(bflo(qb[j]), kf[8 + j * 2],     p);
                p = fmaf(bfhi(qb[j]), kf[8 + j * 2 + 1], p);
            }
            const float score = fmaf(p, SCALE, eb);

            // softmax across heads: lanes differing in bits 0..2 (within group)
            float mx = score;
            mx = fmaxf(mx, __shfl_xor(mx, 1));
            mx = fmaxf(mx, __shfl_xor(mx, 2));
            mx = fmaxf(mx, __shfl_xor(mx, 4));
            const float ex = __expf(score - mx);
            float den = ex;
            den += __shfl_xor(den, 1);
            den += __shfl_xor(den, 2);
            den += __shfl_xor(den, 4);
            float w = __fdividef(ex, den);
            if (i + g >= cnt) w = 0.f;          // mask tail slots

#pragma unroll
            for (int j = 0; j < 4; ++j) {
                acc[j * 2]     = fmaf(w, bflo(va[j]), acc[j * 2]);
                acc[j * 2 + 1] = fmaf(w, bfhi(va[j]), acc[j * 2 + 1]);
            }
#pragma unroll
            for (int j = 0; j < 4; ++j) {
                acc[8 + j * 2]     = fmaf(w, bflo(vb[j]), acc[8 + j * 2]);
                acc[8 + j * 2 + 1] = fmaf(w, bfhi(vb[j]), acc[8 + j * 2 + 1]);
            }

            // rotate pipeline
            qa = qan; qb = qbn; va = van; vb = vbn;
            src_c = src_n; ebw_c = ebw_n;
            src_n = src_f; ebw_n = ebw_f;
        }
    }

    // butterfly reduce across the 8 groups (lane bits 3,4,5)
#pragma unroll
    for (int mask = 8; mask <= 32; mask <<= 1)
#pragma unroll
        for (int d = 0; d < 16; ++d)
            acc[d] += __shfl_xor(acc[d], mask);

    // lane (g,h) writes out[node][h*16 + g*2 .. +1]  (contiguous 512B per wave)
    float2 o2 = make_float2(acc[g * 2], acc[g * 2 + 1]);
    *(float2*)(out + (size_t)node * OUT_DIM + h * 16 + g * 2) = o2;
}

// ---------------------------------------------------------------------------
extern "C" void kernel_launch(void* const* d_in, const int* in_sizes, int n_in,
                              void* d_out, int out_size, void* d_ws, size_t ws_size,
                              hipStream_t stream)
{
    const float* X   = (const float*)d_in[0];
    const float* ef  = (const float*)d_in[1];
    const float* Wq  = (const float*)d_in[2];
    const float* bq  = (const float*)d_in[3];
    const float* Wk  = (const float*)d_in[4];
    const float* bk  = (const float*)d_in[5];
    const float* Wv  = (const float*)d_in[6];
    const float* bv  = (const float*)d_in[7];
    const float* We  = (const float*)d_in[8];
    const float* be  = (const float*)d_in[9];
    const int*   el  = (const int*)d_in[10];

    const int n_nodes = in_sizes[0] / IN_DIM;
    const int n_edges = in_sizes[10] / 2;

    char* w = (char*)d_ws;
    auto alloc = [&](size_t bytes) { char* p = w; w += (bytes + 255) & ~(size_t)255; return p; };

    unsigned short* QVb    = (unsigned short*)alloc((size_t)n_nodes * 256 * 2);
    unsigned short* Kb     = (unsigned short*)alloc((size_t)n_nodes * 128 * 2);
    unsigned short* WtB    = (unsigned short*)alloc((size_t)3 * 128 * 128 * 2);
    unsigned int*   recs   = (unsigned int*)alloc((size_t)n_edges * 32);
    unsigned int*   ebias_e= (unsigned int*)alloc((size_t)n_edges * 16);
    int* rank    = (int*)alloc((size_t)n_edges * 4);
    float* WeR   = (float*)alloc(EDGE_DIM * NUM_HEADS * 4);
    float* beR   = (float*)alloc(NUM_HEADS * 4);
    int* counts  = (int*)alloc((size_t)n_nodes * CSTRIDE * 4);   // padded 64B/ctr
    int* offsets = (int*)alloc((size_t)(n_nodes + 1) * 4);
    int* bsums   = (int*)alloc(256 * 4);

    // Xb (bf16 X) lifetime ends before scatter writes recs -> alias the buffer.
    unsigned short* Xb = (unsigned short*)recs;

    const int nbz = (n_nodes + 255) / 256;          // 196
    const int nbw = (3 * 128 * 128) / 256;          // 192
    const int nbx = (n_nodes * 16 + 255) / 256;     // 3125
    setup_kernel<<<nbz + nbw + 1 + nbx, 256, 0, stream>>>(
        counts, n_nodes, nbz, Wq, Wk, Wv, WtB, nbw, We, be, WeR, beR, X, Xb);

    const int nbh = (n_edges + 255) / 256;          // 3125
    edge_kernel<<<nbh, 256, 0, stream>>>(
        el, counts, rank, ef, WeR, beR, ebias_e, n_edges);

    const int nbm = (n_nodes + 255) / 256;          // 196 (M_BLOCK = 256)
    qkv_kernel<<<3 * nbm, 256, 0, stream>>>(
        Xb, WtB, bq, bk, bv, QVb, Kb, n_nodes, nbm);

    const int nb = (n_nodes + 255) / 256;           // 196
    scan1_kernel<<<nb, 256, 0, stream>>>(counts, bsums, n_nodes);
    scan3_kernel<<<nb, 256, 0, stream>>>(counts, bsums, offsets, n_nodes, n_edges, nb);

    scatter_kernel<<<nbh, 256, 0, stream>>>(
        el, rank, ebias_e, offsets, recs, n_edges);

    aggregate_kernel<<<(n_nodes + 3) / 4, 256, 0, stream>>>(
        QVb, Kb, offsets, recs, (float*)d_out, n_nodes);
}